// Round 1
// baseline (639.171 us; speedup 1.0000x reference)
//
#include <hip/hip_runtime.h>

// ---------------- static problem config ----------------
#define LQN   13294
#define NBAT  2
#define MROWS (NBAT * LQN)   // 26588
#define CCH   256
#define NHEAD 8
#define DHEAD 32
#define NLVL  4
#define NPT   4
#define DFF   2048

typedef short short8 __attribute__((ext_vector_type(8)));
typedef float f32x4 __attribute__((ext_vector_type(4)));
typedef unsigned short u16;
typedef u16 u16x4 __attribute__((ext_vector_type(4)));

__device__ __forceinline__ u16 f2bf(float f) {
  unsigned int u = __builtin_bit_cast(unsigned int, f);
  u += 0x7fffu + ((u >> 16) & 1u);   // RNE
  return (u16)(u >> 16);
}
__device__ __forceinline__ float bf2f(u16 s) {
  unsigned int u = ((unsigned int)s) << 16;
  return __builtin_bit_cast(float, u);
}
__device__ __forceinline__ void async16(const void* g, void* l) {
  __builtin_amdgcn_global_load_lds(
      (const __attribute__((address_space(1))) void*)g,
      (__attribute__((address_space(3))) void*)l, 16, 0, 0);
}

// ---------------- bf16 MFMA GEMM: C[M,N] = A[M,K] * BT[N,K]^T + bias ----------------
// OUT_MODE: 0 = f32 out, 1 = bf16 out, 2 = bf16 out + relu
template<int OUT_MODE>
__global__ __launch_bounds__(256, 2)
void gemm_bf16(const u16* __restrict__ A, const u16* __restrict__ BT,
               const float* __restrict__ bias, void* __restrict__ Cout,
               int M, int N, int K)
{
  __shared__ u16 As[128 * 32];
  __shared__ u16 Bs[128 * 32];
  const int t    = threadIdx.x;
  const int lane = t & 63;
  const int wid  = t >> 6;
  const int wm   = wid >> 1, wn = wid & 1;   // 2x2 waves, 64x64 tile each
  const int bm   = blockIdx.x, bn = blockIdx.y;
  const int l15  = lane & 15;
  const int kg   = (lane >> 4) * 8;

  f32x4 acc[4][4];
#pragma unroll
  for (int m = 0; m < 4; ++m)
#pragma unroll
    for (int n = 0; n < 4; ++n) acc[m][n] = (f32x4)0.0f;

  const int srow = t >> 2;          // staging row within 64-row chunk
  const int skk  = (t & 3) * 8;     // staging k offset (8 bf16 = 16B)

  for (int kt = 0; kt < K; kt += 32) {
#pragma unroll
    for (int r = 0; r < 2; ++r) {
      int row = r * 64 + srow;
      int ar = bm * 128 + row; ar = ar < M ? ar : M - 1;   // M-edge clamp
      async16(&A[(size_t)ar * K + kt + skk], &As[(r * 256 + t) * 8]);
      int br = bn * 128 + row;                              // N multiple of 128
      async16(&BT[(size_t)br * K + kt + skk], &Bs[(r * 256 + t) * 8]);
    }
    __syncthreads();   // drains vmcnt before barrier

    short8 af[4], bfr[4];
#pragma unroll
    for (int m = 0; m < 4; ++m)
      af[m] = *(const short8*)&As[(wm * 64 + m * 16 + l15) * 32 + kg];
#pragma unroll
    for (int n = 0; n < 4; ++n)
      bfr[n] = *(const short8*)&Bs[(wn * 64 + n * 16 + l15) * 32 + kg];
#pragma unroll
    for (int m = 0; m < 4; ++m)
#pragma unroll
      for (int n = 0; n < 4; ++n)
        acc[m][n] = __builtin_amdgcn_mfma_f32_16x16x32_bf16(af[m], bfr[n], acc[m][n], 0, 0, 0);
    __syncthreads();
  }

  const int crow0 = bm * 128 + wm * 64;
  const int ccol0 = bn * 128 + wn * 64;
#pragma unroll
  for (int n = 0; n < 4; ++n) {
    int col = ccol0 + n * 16 + l15;
    float bv = bias[col];
#pragma unroll
    for (int m = 0; m < 4; ++m) {
      int rbase = crow0 + m * 16 + (lane >> 4) * 4;
#pragma unroll
      for (int j = 0; j < 4; ++j) {
        int row = rbase + j;
        if (row < M) {
          float v = acc[m][n][j] + bv;
          if constexpr (OUT_MODE == 0) {
            ((float*)Cout)[(size_t)row * N + col] = v;
          } else {
            if constexpr (OUT_MODE == 2) v = fmaxf(v, 0.0f);
            ((u16*)Cout)[(size_t)row * N + col] = f2bf(v);
          }
        }
      }
    }
  }
}

// ---------------- MS-deform sampler: one block per (b,q) row ----------------
__global__ __launch_bounds__(256)
void sampler_kernel(const float* __restrict__ offattn,   // [M][384] (off 256 | attn 128)
                    const float* __restrict__ refp,      // [M][4][2]
                    const u16*  __restrict__ value,      // [M][256] bf16
                    u16*        __restrict__ src2)       // [M][256] bf16
{
  const int row = blockIdx.x;
  const int b   = row / LQN;
  const int t   = threadIdx.x;
  const int h   = t >> 5, dh = t & 31;

  const float* oa = offattn + (size_t)row * 384;

  // softmax over 16 logits for this head (redundant across 32 lanes)
  float w16[16];
  float mx = -1e30f;
#pragma unroll
  for (int i = 0; i < 16; ++i) { float v = oa[256 + h * 16 + i]; w16[i] = v; mx = fmaxf(mx, v); }
  float se = 0.f;
#pragma unroll
  for (int i = 0; i < 16; ++i) { w16[i] = __expf(w16[i] - mx); se += w16[i]; }
  const float inv = 1.0f / se;

  const float* rp = refp + (size_t)row * 8;
  const u16* vb = value + (size_t)b * LQN * 256 + h * 32 + dh;

  const int SWl[4]   = {100, 50, 25, 13};
  const int SHl[4]   = {100, 50, 25, 13};
  const int START[4] = {0, 10000, 12500, 13125};

  float acc = 0.f;
#pragma unroll
  for (int l = 0; l < NLVL; ++l) {
    const int Wl = SWl[l], Hl = SHl[l], st = START[l];
    const float rx = rp[l * 2 + 0] * (float)Wl - 0.5f;
    const float ry = rp[l * 2 + 1] * (float)Hl - 0.5f;
#pragma unroll
    for (int p = 0; p < NPT; ++p) {
      const float ox = oa[((h * 4 + l) * 4 + p) * 2 + 0];
      const float oy = oa[((h * 4 + l) * 4 + p) * 2 + 1];
      const float gx = rx + ox;            // (rx + ox/Wl)*Wl - 0.5
      const float gy = ry + oy;
      const float aw = w16[l * 4 + p] * inv;
      const float x0f = floorf(gx), y0f = floorf(gy);
      const int x0 = (int)x0f, y0 = (int)y0f;
      const float fx = gx - x0f, fy = gy - y0f;
#pragma unroll
      for (int c = 0; c < 4; ++c) {
        const int dx = c & 1, dy = c >> 1;
        const int xi = x0 + dx, yi = y0 + dy;
        const float wx = dx ? fx : 1.0f - fx;
        const float wy = dy ? fy : 1.0f - fy;
        const bool valid = (xi >= 0) && (xi < Wl) && (yi >= 0) && (yi < Hl);
        const int xc = min(max(xi, 0), Wl - 1);
        const int yc = min(max(yi, 0), Hl - 1);
        const int idx = st + yc * Wl + xc;
        const float g = bf2f(vb[(size_t)idx * 256]);
        acc += g * (wx * wy * aw * (valid ? 1.0f : 0.0f));
      }
    }
  }
  src2[(size_t)row * 256 + t] = f2bf(acc);
}

// ---------------- LayerNorm(Xa + Xb): wave per row ----------------
template<int WRITE_BF>
__global__ __launch_bounds__(256)
void ln_kernel(const float* __restrict__ Xa, const float* __restrict__ Xb,
               const float* __restrict__ gam, const float* __restrict__ bet,
               float* __restrict__ Yf, u16* __restrict__ Ybf)
{
  const int wid = threadIdx.x >> 6, lane = threadIdx.x & 63;
  const int row = blockIdx.x * 4 + wid;        // grid is exact: 6647*4 = 26588
  const f32x4 va = ((const f32x4*)(Xa + (size_t)row * 256))[lane];
  const f32x4 vb = ((const f32x4*)(Xb + (size_t)row * 256))[lane];
  f32x4 v = va + vb;
  float s1 = v[0] + v[1] + v[2] + v[3];
  float s2 = v[0] * v[0] + v[1] * v[1] + v[2] * v[2] + v[3] * v[3];
#pragma unroll
  for (int off = 32; off; off >>= 1) {
    s1 += __shfl_xor(s1, off, 64);
    s2 += __shfl_xor(s2, off, 64);
  }
  const float mean = s1 * (1.0f / 256.0f);
  const float var  = s2 * (1.0f / 256.0f) - mean * mean;
  const float rstd = rsqrtf(var + 1e-5f);
  const f32x4 gv = ((const f32x4*)gam)[lane];
  const f32x4 bv = ((const f32x4*)bet)[lane];
  f32x4 y;
#pragma unroll
  for (int j = 0; j < 4; ++j) y[j] = (v[j] - mean) * rstd * gv[j] + bv[j];
  ((f32x4*)(Yf + (size_t)row * 256))[lane] = y;
  if constexpr (WRITE_BF) {
    u16x4 o;
#pragma unroll
    for (int j = 0; j < 4; ++j) o[j] = f2bf(y[j]);
    ((u16x4*)(Ybf + (size_t)row * 256))[lane] = o;
  }
}

// ---------------- prep: src_bf = bf16(src), q_bf = bf16(src+pos) ----------------
__global__ __launch_bounds__(256)
void prep_qsrc(const float* __restrict__ src, const float* __restrict__ pos,
               u16* __restrict__ src_bf, u16* __restrict__ q_bf)
{
  const size_t i = (size_t)blockIdx.x * 256 + threadIdx.x;   // x4 elems, grid exact
  const f32x4 s = ((const f32x4*)src)[i];
  const f32x4 p = ((const f32x4*)pos)[i];
  u16x4 sb, qb;
#pragma unroll
  for (int j = 0; j < 4; ++j) { sb[j] = f2bf(s[j]); qb[j] = f2bf(s[j] + p[j]); }
  ((u16x4*)src_bf)[i] = sb;
  ((u16x4*)q_bf)[i]   = qb;
}

// ---------------- weight transpose+cast: W[K][N] f32 -> WT[N][K] bf16 ----------------
__global__ __launch_bounds__(256)
void transpose_cast(const float* __restrict__ W, u16* __restrict__ WT, int K, int N)
{
  const int i = blockIdx.x * 256 + threadIdx.x;
  if (i >= K * N) return;
  const int k = i / N, n = i - k * N;
  WT[(size_t)n * K + k] = f2bf(W[i]);
}

__global__ __launch_bounds__(256)
void concat_bias(const float* __restrict__ b_off, const float* __restrict__ b_attn,
                 float* __restrict__ out)
{
  const int i = blockIdx.x * 256 + threadIdx.x;
  if (i < 256) out[i] = b_off[i];
  else if (i < 384) out[i] = b_attn[i - 256];
}

// ---------------- launch ----------------
extern "C" void kernel_launch(void* const* d_in, const int* in_sizes, int n_in,
                              void* d_out, int out_size, void* d_ws, size_t ws_size,
                              hipStream_t stream)
{
  const float* src     = (const float*)d_in[0];
  const float* pos     = (const float*)d_in[1];
  const float* refp    = (const float*)d_in[2];
  const float* w_value = (const float*)d_in[3];
  const float* b_value = (const float*)d_in[4];
  const float* w_off   = (const float*)d_in[5];
  const float* b_off   = (const float*)d_in[6];
  const float* w_attn  = (const float*)d_in[7];
  const float* b_attn  = (const float*)d_in[8];
  const float* w_out   = (const float*)d_in[9];
  const float* b_out   = (const float*)d_in[10];
  const float* ln1_g   = (const float*)d_in[11];
  const float* ln1_b   = (const float*)d_in[12];
  const float* w_ffn1  = (const float*)d_in[13];
  const float* b_ffn1  = (const float*)d_in[14];
  const float* w_ffn2  = (const float*)d_in[15];
  const float* b_ffn2  = (const float*)d_in[16];
  const float* ln2_g   = (const float*)d_in[17];
  const float* ln2_b   = (const float*)d_in[18];

  char* ws = (char*)d_ws;
  size_t off = 0;
  auto alloc = [&](size_t bytes) { void* p = ws + off; off += (bytes + 255) & ~(size_t)255; return p; };

  u16*   src_bf   = (u16*)  alloc((size_t)MROWS * 256 * 2);
  u16*   q_bf     = (u16*)  alloc((size_t)MROWS * 256 * 2);   // later: x_bf
  float* offattn  = (float*)alloc((size_t)MROWS * 384 * 4);   // later: src2p (27.2MB <= 40.8MB)
  u16*   value_bf = (u16*)  alloc((size_t)MROWS * 256 * 2);   // [value_bf|src2_bf] later: ff (f32)
  u16*   src2_bf  = (u16*)  alloc((size_t)MROWS * 256 * 2);
  float* x_f32    = (float*)alloc((size_t)MROWS * 256 * 4);
  u16*   hbuf     = (u16*)  alloc((size_t)MROWS * 2048 * 2);
  u16*   WT_val   = (u16*)  alloc(256 * 256 * 2);
  u16*   WT_oa    = (u16*)  alloc(384 * 256 * 2);
  u16*   WT_out   = (u16*)  alloc(256 * 256 * 2);
  u16*   WT_f1    = (u16*)  alloc(2048 * 256 * 2);
  u16*   WT_f2    = (u16*)  alloc((size_t)256 * 2048 * 2);
  float* bias_oa  = (float*)alloc(384 * 4);

  float* src2p = offattn;            // alias (offattn dead after sampler)
  u16*   x_bf  = q_bf;               // alias (q_bf dead after offattn gemm)
  float* ff    = (float*)value_bf;   // alias (value/src2 dead after out-proj gemm)

  // weight prep (runs every call; tiny)
  transpose_cast<<<256, 256, 0, stream>>>(w_value, WT_val, 256, 256);
  transpose_cast<<<256, 256, 0, stream>>>(w_off, WT_oa, 256, 256);
  transpose_cast<<<128, 256, 0, stream>>>(w_attn, WT_oa + 256 * 256, 256, 128);
  transpose_cast<<<256, 256, 0, stream>>>(w_out, WT_out, 256, 256);
  transpose_cast<<<2048, 256, 0, stream>>>(w_ffn1, WT_f1, 256, 2048);
  transpose_cast<<<2048, 256, 0, stream>>>(w_ffn2, WT_f2, 2048, 256);
  concat_bias<<<2, 256, 0, stream>>>(b_off, b_attn, bias_oa);

  prep_qsrc<<<6647, 256, 0, stream>>>(src, pos, src_bf, q_bf);

  // value = src @ w_value + b  (bf16 out)
  gemm_bf16<1><<<dim3(208, 2), 256, 0, stream>>>(src_bf, WT_val, b_value, value_bf, MROWS, 256, 256);
  // off|attn = q @ [w_off|w_attn] + bias (f32 out)
  gemm_bf16<0><<<dim3(208, 3), 256, 0, stream>>>(q_bf, WT_oa, bias_oa, offattn, MROWS, 384, 256);

  sampler_kernel<<<MROWS, 256, 0, stream>>>(offattn, refp, value_bf, src2_bf);

  // out-proj (f32 out)
  gemm_bf16<0><<<dim3(208, 2), 256, 0, stream>>>(src2_bf, WT_out, b_out, src2p, MROWS, 256, 256);

  // x = LN(src + src2p); also bf16 copy for FFN
  ln_kernel<1><<<6647, 256, 0, stream>>>(src, src2p, ln1_g, ln1_b, x_f32, x_bf);

  // FFN
  gemm_bf16<2><<<dim3(208, 16), 256, 0, stream>>>(x_bf, WT_f1, b_ffn1, hbuf, MROWS, 2048, 256);
  gemm_bf16<0><<<dim3(208, 2), 256, 0, stream>>>(hbuf, WT_f2, b_ffn2, ff, MROWS, 256, 2048);

  // out = LN(x + ff)
  ln_kernel<0><<<6647, 256, 0, stream>>>(x_f32, ff, ln2_g, ln2_b, (float*)d_out, nullptr);
}

// Round 2
// 341.277 us; speedup vs baseline: 1.8729x; 1.8729x over previous
//
#include <hip/hip_runtime.h>

// ---------------- static problem config ----------------
#define LQN   13294
#define NBAT  2
#define MROWS (NBAT * LQN)   // 26588
#define CCH   256
#define NHEAD 8
#define DHEAD 32
#define NLVL  4
#define NPT   4
#define DFF   2048

typedef short short8 __attribute__((ext_vector_type(8)));
typedef float f32x4 __attribute__((ext_vector_type(4)));
typedef unsigned short u16;
typedef u16 u16x4 __attribute__((ext_vector_type(4)));

__device__ __forceinline__ u16 f2bf(float f) {
  unsigned int u = __builtin_bit_cast(unsigned int, f);
  u += 0x7fffu + ((u >> 16) & 1u);   // RNE
  return (u16)(u >> 16);
}
__device__ __forceinline__ float bf2f(u16 s) {
  unsigned int u = ((unsigned int)s) << 16;
  return __builtin_bit_cast(float, u);
}
__device__ __forceinline__ void async16(const void* g, void* l) {
  __builtin_amdgcn_global_load_lds(
      (const __attribute__((address_space(1))) void*)g,
      (__attribute__((address_space(3))) void*)l, 16, 0, 0);
}

// ---------------- bf16 MFMA GEMM: C[M,N] = A[M,K] * BT[N,K]^T + bias ----------------
// OUT_MODE: 0 = f32 out, 1 = bf16 out, 2 = bf16 out + relu
template<int OUT_MODE>
__global__ __launch_bounds__(256, 2)
void gemm_bf16(const u16* __restrict__ A, const u16* __restrict__ BT,
               const float* __restrict__ bias, void* __restrict__ Cout,
               int M, int N, int K)
{
  __shared__ u16 As[128 * 32];
  __shared__ u16 Bs[128 * 32];
  const int t    = threadIdx.x;
  const int lane = t & 63;
  const int wid  = t >> 6;
  const int wm   = wid >> 1, wn = wid & 1;   // 2x2 waves, 64x64 tile each
  const int bm   = blockIdx.x, bn = blockIdx.y;
  const int l15  = lane & 15;
  const int kg   = (lane >> 4) * 8;

  f32x4 acc[4][4];
#pragma unroll
  for (int m = 0; m < 4; ++m)
#pragma unroll
    for (int n = 0; n < 4; ++n) acc[m][n] = (f32x4)0.0f;

  const int srow = t >> 2;          // staging row within 64-row chunk
  const int skk  = (t & 3) * 8;     // staging k offset (8 bf16 = 16B)

  for (int kt = 0; kt < K; kt += 32) {
#pragma unroll
    for (int r = 0; r < 2; ++r) {
      int row = r * 64 + srow;
      int ar = bm * 128 + row; ar = ar < M ? ar : M - 1;   // M-edge clamp
      async16(&A[(size_t)ar * K + kt + skk], &As[(r * 256 + t) * 8]);
      int br = bn * 128 + row;                              // N multiple of 128
      async16(&BT[(size_t)br * K + kt + skk], &Bs[(r * 256 + t) * 8]);
    }
    __syncthreads();   // drains vmcnt before barrier

    short8 af[4], bfr[4];
#pragma unroll
    for (int m = 0; m < 4; ++m)
      af[m] = *(const short8*)&As[(wm * 64 + m * 16 + l15) * 32 + kg];
#pragma unroll
    for (int n = 0; n < 4; ++n)
      bfr[n] = *(const short8*)&Bs[(wn * 64 + n * 16 + l15) * 32 + kg];
#pragma unroll
    for (int m = 0; m < 4; ++m)
#pragma unroll
      for (int n = 0; n < 4; ++n)
        acc[m][n] = __builtin_amdgcn_mfma_f32_16x16x32_bf16(af[m], bfr[n], acc[m][n], 0, 0, 0);
    __syncthreads();
  }

  const int crow0 = bm * 128 + wm * 64;
  const int ccol0 = bn * 128 + wn * 64;
#pragma unroll
  for (int n = 0; n < 4; ++n) {
    int col = ccol0 + n * 16 + l15;
    float bv = bias[col];
#pragma unroll
    for (int m = 0; m < 4; ++m) {
      int rbase = crow0 + m * 16 + (lane >> 4) * 4;
#pragma unroll
      for (int j = 0; j < 4; ++j) {
        int row = rbase + j;
        if (row < M) {
          float v = acc[m][n][j] + bv;
          if constexpr (OUT_MODE == 0) {
            ((float*)Cout)[(size_t)row * N + col] = v;
          } else {
            if constexpr (OUT_MODE == 2) v = fmaxf(v, 0.0f);
            ((u16*)Cout)[(size_t)row * N + col] = f2bf(v);
          }
        }
      }
    }
  }
}

// ---------------- MS-deform sampler v2 ----------------
// Block = 256 threads handles 2 rows.
// Stage 1: 128 threads/row precompute (weight, index) for 8 heads x 16 points x 4
//          corners into LDS (softmax via 16-lane shuffle reduce).
// Stage 2: 128 threads/row gather: lane owns 2 channels (u32 loads), loops 64
//          LDS entries (broadcast reads), 2 FMA each.
__global__ __launch_bounds__(256)
void sampler_kernel(const float* __restrict__ offattn,   // [M][384] (off 256 | attn 128)
                    const float* __restrict__ refp,      // [M][4][2]
                    const u16*  __restrict__ value,      // [M][256] bf16
                    u16*        __restrict__ src2)       // [M][256] bf16
{
  __shared__ float2 sWI[2][8][65];   // [row2][head][64 entries + pad]

  const int t   = threadIdx.x;
  const int r2  = t >> 7;            // row within block
  const int g   = t & 127;
  const int row = blockIdx.x * 2 + r2;
  const int b   = row / LQN;

  // ---- stage 1: weights ----
  {
    const int h   = g >> 4;          // 0..7
    const int p16 = g & 15;          // l*4+p
    const int l   = p16 >> 2;

    const float* oa = offattn + (size_t)row * 384;

    // softmax over the 16 points of this head (16-lane group reduce)
    float logit = oa[256 + h * 16 + p16];
    float mx = logit;
#pragma unroll
    for (int o = 1; o < 16; o <<= 1) mx = fmaxf(mx, __shfl_xor(mx, o, 64));
    float e = __expf(logit - mx);
    float s = e;
#pragma unroll
    for (int o = 1; o < 16; o <<= 1) s += __shfl_xor(s, o, 64);
    const float aw = e / s;

    const int Wl = (l == 0) ? 100 : (l == 1) ? 50 : (l == 2) ? 25 : 13;
    const int Hl = Wl;
    const int st = (l == 0) ? 0 : (l == 1) ? 10000 : (l == 2) ? 12500 : 13125;

    const float ox = oa[(h * 16 + p16) * 2 + 0];
    const float oy = oa[(h * 16 + p16) * 2 + 1];
    const float rx = refp[(size_t)row * 8 + l * 2 + 0] * (float)Wl - 0.5f;
    const float ry = refp[(size_t)row * 8 + l * 2 + 1] * (float)Hl - 0.5f;
    const float gx = rx + ox;       // (r + off/W)*W - 0.5
    const float gy = ry + oy;
    const float x0f = floorf(gx), y0f = floorf(gy);
    const int   x0 = (int)x0f, y0 = (int)y0f;
    const float fx = gx - x0f, fy = gy - y0f;

#pragma unroll
    for (int c = 0; c < 4; ++c) {
      const int dx = c & 1, dy = c >> 1;
      const int xi = x0 + dx, yi = y0 + dy;
      const float wx = dx ? fx : 1.0f - fx;
      const float wy = dy ? fy : 1.0f - fy;
      const bool valid = (xi >= 0) && (xi < Wl) && (yi >= 0) && (yi < Hl);
      const int xc = min(max(xi, 0), Wl - 1);
      const int yc = min(max(yi, 0), Hl - 1);
      const int idx = st + yc * Wl + xc;
      const float w = wx * wy * aw * (valid ? 1.0f : 0.0f);
      sWI[r2][h][p16 * 4 + c] = make_float2(w, __builtin_bit_cast(float, idx));
    }
  }
  __syncthreads();

  // ---- stage 2: gather ----
  {
    const int h  = g >> 4;           // 0..7
    const int c2 = g & 15;           // channel pair: ch = 2*c2, 2*c2+1
    const char* vbase = (const char*)value + (size_t)b * LQN * 512 + h * 64 + c2 * 4;
    const float2* wi = sWI[r2][h];

    float acc0 = 0.f, acc1 = 0.f;
#pragma unroll 16
    for (int e = 0; e < 64; ++e) {
      const float2 p = wi[e];        // broadcast within 16-lane group
      const float w  = p.x;
      const int  idx = __builtin_bit_cast(int, p.y);
      const unsigned u = *(const unsigned*)(vbase + (size_t)idx * 512);
      const float f0 = __builtin_bit_cast(float, u << 16);
      const float f1 = __builtin_bit_cast(float, u & 0xffff0000u);
      acc0 += f0 * w;
      acc1 += f1 * w;
    }
    const unsigned o = (unsigned)f2bf(acc0) | ((unsigned)f2bf(acc1) << 16);
    *(unsigned*)&src2[(size_t)row * 256 + h * 32 + c2 * 2] = o;
  }
}

// ---------------- LayerNorm(Xa + Xb): wave per row ----------------
template<int WRITE_BF>
__global__ __launch_bounds__(256)
void ln_kernel(const float* __restrict__ Xa, const float* __restrict__ Xb,
               const float* __restrict__ gam, const float* __restrict__ bet,
               float* __restrict__ Yf, u16* __restrict__ Ybf)
{
  const int wid = threadIdx.x >> 6, lane = threadIdx.x & 63;
  const int row = blockIdx.x * 4 + wid;        // grid is exact: 6647*4 = 26588
  const f32x4 va = ((const f32x4*)(Xa + (size_t)row * 256))[lane];
  const f32x4 vb = ((const f32x4*)(Xb + (size_t)row * 256))[lane];
  f32x4 v = va + vb;
  float s1 = v[0] + v[1] + v[2] + v[3];
  float s2 = v[0] * v[0] + v[1] * v[1] + v[2] * v[2] + v[3] * v[3];
#pragma unroll
  for (int off = 32; off; off >>= 1) {
    s1 += __shfl_xor(s1, off, 64);
    s2 += __shfl_xor(s2, off, 64);
  }
  const float mean = s1 * (1.0f / 256.0f);
  const float var  = s2 * (1.0f / 256.0f) - mean * mean;
  const float rstd = rsqrtf(var + 1e-5f);
  const f32x4 gv = ((const f32x4*)gam)[lane];
  const f32x4 bv = ((const f32x4*)bet)[lane];
  f32x4 y;
#pragma unroll
  for (int j = 0; j < 4; ++j) y[j] = (v[j] - mean) * rstd * gv[j] + bv[j];
  ((f32x4*)(Yf + (size_t)row * 256))[lane] = y;
  if constexpr (WRITE_BF) {
    u16x4 o;
#pragma unroll
    for (int j = 0; j < 4; ++j) o[j] = f2bf(y[j]);
    ((u16x4*)(Ybf + (size_t)row * 256))[lane] = o;
  }
}

// ---------------- prep: src_bf = bf16(src), q_bf = bf16(src+pos) ----------------
__global__ __launch_bounds__(256)
void prep_qsrc(const float* __restrict__ src, const float* __restrict__ pos,
               u16* __restrict__ src_bf, u16* __restrict__ q_bf)
{
  const size_t i = (size_t)blockIdx.x * 256 + threadIdx.x;   // x4 elems, grid exact
  const f32x4 s = ((const f32x4*)src)[i];
  const f32x4 p = ((const f32x4*)pos)[i];
  u16x4 sb, qb;
#pragma unroll
  for (int j = 0; j < 4; ++j) { sb[j] = f2bf(s[j]); qb[j] = f2bf(s[j] + p[j]); }
  ((u16x4*)src_bf)[i] = sb;
  ((u16x4*)q_bf)[i]   = qb;
}

// ---------------- weight transpose+cast: W[K][N] f32 -> WT[N][K] bf16 ----------------
__global__ __launch_bounds__(256)
void transpose_cast(const float* __restrict__ W, u16* __restrict__ WT, int K, int N)
{
  const int i = blockIdx.x * 256 + threadIdx.x;
  if (i >= K * N) return;
  const int k = i / N, n = i - k * N;
  WT[(size_t)n * K + k] = f2bf(W[i]);
}

__global__ __launch_bounds__(256)
void concat_bias(const float* __restrict__ b_off, const float* __restrict__ b_attn,
                 float* __restrict__ out)
{
  const int i = blockIdx.x * 256 + threadIdx.x;
  if (i < 256) out[i] = b_off[i];
  else if (i < 384) out[i] = b_attn[i - 256];
}

// ---------------- launch ----------------
extern "C" void kernel_launch(void* const* d_in, const int* in_sizes, int n_in,
                              void* d_out, int out_size, void* d_ws, size_t ws_size,
                              hipStream_t stream)
{
  const float* src     = (const float*)d_in[0];
  const float* pos     = (const float*)d_in[1];
  const float* refp    = (const float*)d_in[2];
  const float* w_value = (const float*)d_in[3];
  const float* b_value = (const float*)d_in[4];
  const float* w_off   = (const float*)d_in[5];
  const float* b_off   = (const float*)d_in[6];
  const float* w_attn  = (const float*)d_in[7];
  const float* b_attn  = (const float*)d_in[8];
  const float* w_out   = (const float*)d_in[9];
  const float* b_out   = (const float*)d_in[10];
  const float* ln1_g   = (const float*)d_in[11];
  const float* ln1_b   = (const float*)d_in[12];
  const float* w_ffn1  = (const float*)d_in[13];
  const float* b_ffn1  = (const float*)d_in[14];
  const float* w_ffn2  = (const float*)d_in[15];
  const float* b_ffn2  = (const float*)d_in[16];
  const float* ln2_g   = (const float*)d_in[17];
  const float* ln2_b   = (const float*)d_in[18];

  char* ws = (char*)d_ws;
  size_t off = 0;
  auto alloc = [&](size_t bytes) { void* p = ws + off; off += (bytes + 255) & ~(size_t)255; return p; };

  u16*   src_bf   = (u16*)  alloc((size_t)MROWS * 256 * 2);
  u16*   q_bf     = (u16*)  alloc((size_t)MROWS * 256 * 2);   // later: x_bf
  float* offattn  = (float*)alloc((size_t)MROWS * 384 * 4);   // later: src2p
  u16*   value_bf = (u16*)  alloc((size_t)MROWS * 256 * 2);   // later: ff (f32, with src2_bf)
  u16*   src2_bf  = (u16*)  alloc((size_t)MROWS * 256 * 2);
  float* x_f32    = (float*)alloc((size_t)MROWS * 256 * 4);
  u16*   hbuf     = (u16*)  alloc((size_t)MROWS * 2048 * 2);
  u16*   WT_val   = (u16*)  alloc(256 * 256 * 2);
  u16*   WT_oa    = (u16*)  alloc(384 * 256 * 2);
  u16*   WT_out   = (u16*)  alloc(256 * 256 * 2);
  u16*   WT_f1    = (u16*)  alloc(2048 * 256 * 2);
  u16*   WT_f2    = (u16*)  alloc((size_t)256 * 2048 * 2);
  float* bias_oa  = (float*)alloc(384 * 4);

  float* src2p = offattn;            // alias (offattn dead after sampler)
  u16*   x_bf  = q_bf;               // alias (q_bf dead after offattn gemm)
  float* ff    = (float*)value_bf;   // alias (value/src2 dead after out-proj gemm)

  // weight prep (runs every call; tiny)
  transpose_cast<<<256, 256, 0, stream>>>(w_value, WT_val, 256, 256);
  transpose_cast<<<256, 256, 0, stream>>>(w_off, WT_oa, 256, 256);
  transpose_cast<<<128, 256, 0, stream>>>(w_attn, WT_oa + 256 * 256, 256, 128);
  transpose_cast<<<256, 256, 0, stream>>>(w_out, WT_out, 256, 256);
  transpose_cast<<<2048, 256, 0, stream>>>(w_ffn1, WT_f1, 256, 2048);
  transpose_cast<<<2048, 256, 0, stream>>>(w_ffn2, WT_f2, 2048, 256);
  concat_bias<<<2, 256, 0, stream>>>(b_off, b_attn, bias_oa);

  prep_qsrc<<<6647, 256, 0, stream>>>(src, pos, src_bf, q_bf);

  // value = src @ w_value + b  (bf16 out)
  gemm_bf16<1><<<dim3(208, 2), 256, 0, stream>>>(src_bf, WT_val, b_value, value_bf, MROWS, 256, 256);
  // off|attn = q @ [w_off|w_attn] + bias (f32 out)
  gemm_bf16<0><<<dim3(208, 3), 256, 0, stream>>>(q_bf, WT_oa, bias_oa, offattn, MROWS, 384, 256);

  sampler_kernel<<<MROWS / 2, 256, 0, stream>>>(offattn, refp, value_bf, src2_bf);

  // out-proj (f32 out)
  gemm_bf16<0><<<dim3(208, 2), 256, 0, stream>>>(src2_bf, WT_out, b_out, src2p, MROWS, 256, 256);

  // x = LN(src + src2p); also bf16 copy for FFN
  ln_kernel<1><<<6647, 256, 0, stream>>>(src, src2p, ln1_g, ln1_b, x_f32, x_bf);

  // FFN
  gemm_bf16<2><<<dim3(208, 16), 256, 0, stream>>>(x_bf, WT_f1, b_ffn1, hbuf, MROWS, 2048, 256);
  gemm_bf16<0><<<dim3(208, 2), 256, 0, stream>>>(hbuf, WT_f2, b_ffn2, ff, MROWS, 256, 2048);

  // out = LN(x + ff)
  ln_kernel<0><<<6647, 256, 0, stream>>>(x_f32, ff, ln2_g, ln2_b, (float*)d_out, nullptr);
}

// Round 3
// 336.179 us; speedup vs baseline: 1.9013x; 1.0152x over previous
//
#include <hip/hip_runtime.h>

// ---------------- static problem config ----------------
#define LQN   13294
#define NBAT  2
#define MROWS (NBAT * LQN)   // 26588
#define CCH   256
#define NHEAD 8
#define DHEAD 32
#define NLVL  4
#define NPT   4
#define DFF   2048

typedef short short8 __attribute__((ext_vector_type(8)));
typedef float f32x4 __attribute__((ext_vector_type(4)));
typedef unsigned short u16;
typedef u16 u16x4 __attribute__((ext_vector_type(4)));

__device__ __forceinline__ u16 f2bf(float f) {
  unsigned int u = __builtin_bit_cast(unsigned int, f);
  u += 0x7fffu + ((u >> 16) & 1u);   // RNE
  return (u16)(u >> 16);
}
__device__ __forceinline__ float bf2f(u16 s) {
  unsigned int u = ((unsigned int)s) << 16;
  return __builtin_bit_cast(float, u);
}
__device__ __forceinline__ void async16(const void* g, void* l) {
  __builtin_amdgcn_global_load_lds(
      (const __attribute__((address_space(1))) void*)g,
      (__attribute__((address_space(3))) void*)l, 16, 0, 0);
}

// ---------------- bf16 MFMA GEMM v2: 2-phase double-buffered prefetch ----------------
// C[M,N] = A[M,K] * BT[N,K]^T + bias.  BM=BN=128, BK=64, 4 waves (2x2), 64KB LDS.
// k-chunk XOR swizzle applied on the *global source* during staging (LDS dest stays
// linear, as global_load_lds requires) and on the ds_read address (same involution).
// OUT_MODE: 0 = f32 out, 1 = bf16 out, 2 = bf16 out + relu
template<int OUT_MODE>
__global__ __launch_bounds__(256, 2)
void gemm_bf16(const u16* __restrict__ A, const u16* __restrict__ BT,
               const float* __restrict__ bias, void* __restrict__ Cout,
               int M, int N, int K)
{
  __shared__ u16 As[2][128 * 64];
  __shared__ u16 Bs[2][128 * 64];
  const int t    = threadIdx.x;
  const int lane = t & 63;
  const int wid  = t >> 6;
  const int wm   = wid >> 1, wn = wid & 1;   // 2x2 waves, 64x64 tile each
  const int bm   = blockIdx.x, bn = blockIdx.y;
  const int l15  = lane & 15;
  const int kq   = lane >> 4;                // k-quarter 0..3

  f32x4 acc[4][4];
#pragma unroll
  for (int m = 0; m < 4; ++m)
#pragma unroll
    for (int n = 0; n < 4; ++n) acc[m][n] = (f32x4)0.0f;

  // staging: 1024 16B-chunks per matrix per tile; thread t does chunks t+256*i.
  // chunk c -> LDS byte c*16 (linear; wave-uniform base + lane*16).
  // content: row = c>>3, k-chunk kg = (c&7) ^ (row&7)  [source-side swizzle]
  auto stage = [&](int buf, int kt) {
#pragma unroll
    for (int i = 0; i < 4; ++i) {
      const int c   = i * 256 + t;
      const int row = c >> 3;
      const int kg  = (c & 7) ^ (row & 7);
      int ar = bm * 128 + row; ar = ar < M ? ar : M - 1;   // M-edge clamp
      async16(&A[(size_t)ar * K + kt + kg * 8], &As[buf][c * 8]);
      const int br = bn * 128 + row;                        // N multiple of 128
      async16(&BT[(size_t)br * K + kt + kg * 8], &Bs[buf][c * 8]);
    }
  };

  stage(0, 0);
  __syncthreads();            // drain prologue loads
  int cur = 0;

  for (int kt = 0; kt < K; kt += 64) {
    if (kt + 64 < K) stage(cur ^ 1, kt + 64);   // prefetch next tile (stays in flight)

#pragma unroll
    for (int kk = 0; kk < 2; ++kk) {
      short8 af[4], bfr[4];
#pragma unroll
      for (int m = 0; m < 4; ++m) {
        const int row = wm * 64 + m * 16 + l15;
        const int xb  = (kk * 64 + kq * 16) ^ ((row & 7) << 4);
        af[m] = *(const short8*)((const char*)&As[cur][0] + row * 128 + xb);
      }
#pragma unroll
      for (int n = 0; n < 4; ++n) {
        const int col = wn * 64 + n * 16 + l15;
        const int xb  = (kk * 64 + kq * 16) ^ ((col & 7) << 4);
        bfr[n] = *(const short8*)((const char*)&Bs[cur][0] + col * 128 + xb);
      }
#pragma unroll
      for (int m = 0; m < 4; ++m)
#pragma unroll
        for (int n = 0; n < 4; ++n)
          acc[m][n] = __builtin_amdgcn_mfma_f32_16x16x32_bf16(af[m], bfr[n], acc[m][n], 0, 0, 0);
    }

    __syncthreads();          // waits for this iter's prefetch; all waves done with cur
    cur ^= 1;
  }

  const int crow0 = bm * 128 + wm * 64;
  const int ccol0 = bn * 128 + wn * 64;
#pragma unroll
  for (int n = 0; n < 4; ++n) {
    int col = ccol0 + n * 16 + l15;
    float bv = bias[col];
#pragma unroll
    for (int m = 0; m < 4; ++m) {
      int rbase = crow0 + m * 16 + kq * 4;
#pragma unroll
      for (int j = 0; j < 4; ++j) {
        int row = rbase + j;
        if (row < M) {
          float v = acc[m][n][j] + bv;
          if constexpr (OUT_MODE == 0) {
            ((float*)Cout)[(size_t)row * N + col] = v;
          } else {
            if constexpr (OUT_MODE == 2) v = fmaxf(v, 0.0f);
            ((u16*)Cout)[(size_t)row * N + col] = f2bf(v);
          }
        }
      }
    }
  }
}

// ---------------- MS-deform sampler v2 ----------------
__global__ __launch_bounds__(256)
void sampler_kernel(const float* __restrict__ offattn,   // [M][384] (off 256 | attn 128)
                    const float* __restrict__ refp,      // [M][4][2]
                    const u16*  __restrict__ value,      // [M][256] bf16
                    u16*        __restrict__ src2)       // [M][256] bf16
{
  __shared__ float2 sWI[2][8][65];   // [row2][head][64 entries + pad]

  const int t   = threadIdx.x;
  const int r2  = t >> 7;            // row within block
  const int g   = t & 127;
  const int row = blockIdx.x * 2 + r2;
  const int b   = row / LQN;

  // ---- stage 1: weights ----
  {
    const int h   = g >> 4;          // 0..7
    const int p16 = g & 15;          // l*4+p
    const int l   = p16 >> 2;

    const float* oa = offattn + (size_t)row * 384;

    float logit = oa[256 + h * 16 + p16];
    float mx = logit;
#pragma unroll
    for (int o = 1; o < 16; o <<= 1) mx = fmaxf(mx, __shfl_xor(mx, o, 64));
    float e = __expf(logit - mx);
    float s = e;
#pragma unroll
    for (int o = 1; o < 16; o <<= 1) s += __shfl_xor(s, o, 64);
    const float aw = e / s;

    const int Wl = (l == 0) ? 100 : (l == 1) ? 50 : (l == 2) ? 25 : 13;
    const int Hl = Wl;
    const int st = (l == 0) ? 0 : (l == 1) ? 10000 : (l == 2) ? 12500 : 13125;

    const float ox = oa[(h * 16 + p16) * 2 + 0];
    const float oy = oa[(h * 16 + p16) * 2 + 1];
    const float rx = refp[(size_t)row * 8 + l * 2 + 0] * (float)Wl - 0.5f;
    const float ry = refp[(size_t)row * 8 + l * 2 + 1] * (float)Hl - 0.5f;
    const float gx = rx + ox;
    const float gy = ry + oy;
    const float x0f = floorf(gx), y0f = floorf(gy);
    const int   x0 = (int)x0f, y0 = (int)y0f;
    const float fx = gx - x0f, fy = gy - y0f;

#pragma unroll
    for (int c = 0; c < 4; ++c) {
      const int dx = c & 1, dy = c >> 1;
      const int xi = x0 + dx, yi = y0 + dy;
      const float wx = dx ? fx : 1.0f - fx;
      const float wy = dy ? fy : 1.0f - fy;
      const bool valid = (xi >= 0) && (xi < Wl) && (yi >= 0) && (yi < Hl);
      const int xc = min(max(xi, 0), Wl - 1);
      const int yc = min(max(yi, 0), Hl - 1);
      const int idx = st + yc * Wl + xc;
      const float w = wx * wy * aw * (valid ? 1.0f : 0.0f);
      sWI[r2][h][p16 * 4 + c] = make_float2(w, __builtin_bit_cast(float, idx));
    }
  }
  __syncthreads();

  // ---- stage 2: gather ----
  {
    const int h  = g >> 4;
    const int c2 = g & 15;           // channel pair
    const char* vbase = (const char*)value + (size_t)b * LQN * 512 + h * 64 + c2 * 4;
    const float2* wi = sWI[r2][h];

    float acc0 = 0.f, acc1 = 0.f;
#pragma unroll 16
    for (int e = 0; e < 64; ++e) {
      const float2 p = wi[e];
      const float w  = p.x;
      const int  idx = __builtin_bit_cast(int, p.y);
      const unsigned u = *(const unsigned*)(vbase + (size_t)idx * 512);
      const float f0 = __builtin_bit_cast(float, u << 16);
      const float f1 = __builtin_bit_cast(float, u & 0xffff0000u);
      acc0 += f0 * w;
      acc1 += f1 * w;
    }
    const unsigned o = (unsigned)f2bf(acc0) | ((unsigned)f2bf(acc1) << 16);
    *(unsigned*)&src2[(size_t)row * 256 + h * 32 + c2 * 2] = o;
  }
}

// ---------------- LayerNorm(Xa + Xb): wave per row ----------------
template<int WRITE_BF>
__global__ __launch_bounds__(256)
void ln_kernel(const float* __restrict__ Xa, const float* __restrict__ Xb,
               const float* __restrict__ gam, const float* __restrict__ bet,
               float* __restrict__ Yf, u16* __restrict__ Ybf)
{
  const int wid = threadIdx.x >> 6, lane = threadIdx.x & 63;
  const int row = blockIdx.x * 4 + wid;        // grid is exact: 6647*4 = 26588
  const f32x4 va = ((const f32x4*)(Xa + (size_t)row * 256))[lane];
  const f32x4 vb = ((const f32x4*)(Xb + (size_t)row * 256))[lane];
  f32x4 v = va + vb;
  float s1 = v[0] + v[1] + v[2] + v[3];
  float s2 = v[0] * v[0] + v[1] * v[1] + v[2] * v[2] + v[3] * v[3];
#pragma unroll
  for (int off = 32; off; off >>= 1) {
    s1 += __shfl_xor(s1, off, 64);
    s2 += __shfl_xor(s2, off, 64);
  }
  const float mean = s1 * (1.0f / 256.0f);
  const float var  = s2 * (1.0f / 256.0f) - mean * mean;
  const float rstd = rsqrtf(var + 1e-5f);
  const f32x4 gv = ((const f32x4*)gam)[lane];
  const f32x4 bv = ((const f32x4*)bet)[lane];
  f32x4 y;
#pragma unroll
  for (int j = 0; j < 4; ++j) y[j] = (v[j] - mean) * rstd * gv[j] + bv[j];
  ((f32x4*)(Yf + (size_t)row * 256))[lane] = y;
  if constexpr (WRITE_BF) {
    u16x4 o;
#pragma unroll
    for (int j = 0; j < 4; ++j) o[j] = f2bf(y[j]);
    ((u16x4*)(Ybf + (size_t)row * 256))[lane] = o;
  }
}

// ---------------- prep: src_bf = bf16(src), q_bf = bf16(src+pos) ----------------
__global__ __launch_bounds__(256)
void prep_qsrc(const float* __restrict__ src, const float* __restrict__ pos,
               u16* __restrict__ src_bf, u16* __restrict__ q_bf)
{
  const size_t i = (size_t)blockIdx.x * 256 + threadIdx.x;   // x4 elems, grid exact
  const f32x4 s = ((const f32x4*)src)[i];
  const f32x4 p = ((const f32x4*)pos)[i];
  u16x4 sb, qb;
#pragma unroll
  for (int j = 0; j < 4; ++j) { sb[j] = f2bf(s[j]); qb[j] = f2bf(s[j] + p[j]); }
  ((u16x4*)src_bf)[i] = sb;
  ((u16x4*)q_bf)[i]   = qb;
}

// ---------------- weight transpose+cast: W[K][N] f32 -> WT[N][K] bf16 ----------------
__global__ __launch_bounds__(256)
void transpose_cast(const float* __restrict__ W, u16* __restrict__ WT, int K, int N)
{
  const int i = blockIdx.x * 256 + threadIdx.x;
  if (i >= K * N) return;
  const int k = i / N, n = i - k * N;
  WT[(size_t)n * K + k] = f2bf(W[i]);
}

__global__ __launch_bounds__(256)
void concat_bias(const float* __restrict__ b_off, const float* __restrict__ b_attn,
                 float* __restrict__ out)
{
  const int i = blockIdx.x * 256 + threadIdx.x;
  if (i < 256) out[i] = b_off[i];
  else if (i < 384) out[i] = b_attn[i - 256];
}

// ---------------- launch ----------------
extern "C" void kernel_launch(void* const* d_in, const int* in_sizes, int n_in,
                              void* d_out, int out_size, void* d_ws, size_t ws_size,
                              hipStream_t stream)
{
  const float* src     = (const float*)d_in[0];
  const float* pos     = (const float*)d_in[1];
  const float* refp    = (const float*)d_in[2];
  const float* w_value = (const float*)d_in[3];
  const float* b_value = (const float*)d_in[4];
  const float* w_off   = (const float*)d_in[5];
  const float* b_off   = (const float*)d_in[6];
  const float* w_attn  = (const float*)d_in[7];
  const float* b_attn  = (const float*)d_in[8];
  const float* w_out   = (const float*)d_in[9];
  const float* b_out   = (const float*)d_in[10];
  const float* ln1_g   = (const float*)d_in[11];
  const float* ln1_b   = (const float*)d_in[12];
  const float* w_ffn1  = (const float*)d_in[13];
  const float* b_ffn1  = (const float*)d_in[14];
  const float* w_ffn2  = (const float*)d_in[15];
  const float* b_ffn2  = (const float*)d_in[16];
  const float* ln2_g   = (const float*)d_in[17];
  const float* ln2_b   = (const float*)d_in[18];

  char* ws = (char*)d_ws;
  size_t off = 0;
  auto alloc = [&](size_t bytes) { void* p = ws + off; off += (bytes + 255) & ~(size_t)255; return p; };

  u16*   src_bf   = (u16*)  alloc((size_t)MROWS * 256 * 2);
  u16*   q_bf     = (u16*)  alloc((size_t)MROWS * 256 * 2);   // later: x_bf
  float* offattn  = (float*)alloc((size_t)MROWS * 384 * 4);   // later: src2p
  u16*   value_bf = (u16*)  alloc((size_t)MROWS * 256 * 2);   // later: ff (f32, with src2_bf)
  u16*   src2_bf  = (u16*)  alloc((size_t)MROWS * 256 * 2);
  float* x_f32    = (float*)alloc((size_t)MROWS * 256 * 4);
  u16*   hbuf     = (u16*)  alloc((size_t)MROWS * 2048 * 2);
  u16*   WT_val   = (u16*)  alloc(256 * 256 * 2);
  u16*   WT_oa    = (u16*)  alloc(384 * 256 * 2);
  u16*   WT_out   = (u16*)  alloc(256 * 256 * 2);
  u16*   WT_f1    = (u16*)  alloc(2048 * 256 * 2);
  u16*   WT_f2    = (u16*)  alloc((size_t)256 * 2048 * 2);
  float* bias_oa  = (float*)alloc(384 * 4);

  float* src2p = offattn;            // alias (offattn dead after sampler)
  u16*   x_bf  = q_bf;               // alias (q_bf dead after offattn gemm)
  float* ff    = (float*)value_bf;   // alias (value/src2 dead after out-proj gemm)

  // weight prep (runs every call; tiny)
  transpose_cast<<<256, 256, 0, stream>>>(w_value, WT_val, 256, 256);
  transpose_cast<<<256, 256, 0, stream>>>(w_off, WT_oa, 256, 256);
  transpose_cast<<<128, 256, 0, stream>>>(w_attn, WT_oa + 256 * 256, 256, 128);
  transpose_cast<<<256, 256, 0, stream>>>(w_out, WT_out, 256, 256);
  transpose_cast<<<2048, 256, 0, stream>>>(w_ffn1, WT_f1, 256, 2048);
  transpose_cast<<<2048, 256, 0, stream>>>(w_ffn2, WT_f2, 2048, 256);
  concat_bias<<<2, 256, 0, stream>>>(b_off, b_attn, bias_oa);

  prep_qsrc<<<6647, 256, 0, stream>>>(src, pos, src_bf, q_bf);

  // value = src @ w_value + b  (bf16 out)
  gemm_bf16<1><<<dim3(208, 2), 256, 0, stream>>>(src_bf, WT_val, b_value, value_bf, MROWS, 256, 256);
  // off|attn = q @ [w_off|w_attn] + bias (f32 out)
  gemm_bf16<0><<<dim3(208, 3), 256, 0, stream>>>(q_bf, WT_oa, bias_oa, offattn, MROWS, 384, 256);

  sampler_kernel<<<MROWS / 2, 256, 0, stream>>>(offattn, refp, value_bf, src2_bf);

  // out-proj (f32 out)
  gemm_bf16<0><<<dim3(208, 2), 256, 0, stream>>>(src2_bf, WT_out, b_out, src2p, MROWS, 256, 256);

  // x = LN(src + src2p); also bf16 copy for FFN
  ln_kernel<1><<<6647, 256, 0, stream>>>(src, src2p, ln1_g, ln1_b, x_f32, x_bf);

  // FFN
  gemm_bf16<2><<<dim3(208, 16), 256, 0, stream>>>(x_bf, WT_f1, b_ffn1, hbuf, MROWS, 2048, 256);
  gemm_bf16<0><<<dim3(208, 2), 256, 0, stream>>>(hbuf, WT_f2, b_ffn2, ff, MROWS, 256, 2048);

  // out = LN(x + ff)
  ln_kernel<0><<<6647, 256, 0, stream>>>(x_f32, ff, ln2_g, ln2_b, (float*)d_out, nullptr);
}

// Round 4
// 287.900 us; speedup vs baseline: 2.2201x; 1.1677x over previous
//
#include <hip/hip_runtime.h>

// ---------------- static problem config ----------------
#define LQN   13294
#define NBAT  2
#define MROWS (NBAT * LQN)   // 26588
#define CCH   256
#define NHEAD 8
#define DHEAD 32
#define NLVL  4
#define NPT   4
#define DFF   2048

typedef short short8 __attribute__((ext_vector_type(8)));
typedef float f32x4 __attribute__((ext_vector_type(4)));
typedef unsigned short u16;
typedef u16 u16x4 __attribute__((ext_vector_type(4)));

__device__ __forceinline__ u16 f2bf(float f) {
  unsigned int u = __builtin_bit_cast(unsigned int, f);
  u += 0x7fffu + ((u >> 16) & 1u);   // RNE
  return (u16)(u >> 16);
}
__device__ __forceinline__ float bf2f(u16 s) {
  unsigned int u = ((unsigned int)s) << 16;
  return __builtin_bit_cast(float, u);
}
__device__ __forceinline__ void async16(const void* g, void* l) {
  __builtin_amdgcn_global_load_lds(
      (const __attribute__((address_space(1))) void*)g,
      (__attribute__((address_space(3))) void*)l, 16, 0, 0);
}

// ---------------- bf16 MFMA GEMM (r3): 2-phase dbuf, swizzled ----------------
// OUT_MODE: 0 = f32 out, 1 = bf16 out, 2 = bf16 out + relu
template<int OUT_MODE>
__global__ __launch_bounds__(256, 2)
void gemm_bf16(const u16* __restrict__ A, const u16* __restrict__ BT,
               const float* __restrict__ bias, void* __restrict__ Cout,
               int M, int N, int K)
{
  __shared__ u16 As[2][128 * 64];
  __shared__ u16 Bs[2][128 * 64];
  const int t    = threadIdx.x;
  const int lane = t & 63;
  const int wid  = t >> 6;
  const int wm   = wid >> 1, wn = wid & 1;
  const int bm   = blockIdx.x, bn = blockIdx.y;
  const int l15  = lane & 15;
  const int kq   = lane >> 4;

  f32x4 acc[4][4];
#pragma unroll
  for (int m = 0; m < 4; ++m)
#pragma unroll
    for (int n = 0; n < 4; ++n) acc[m][n] = (f32x4)0.0f;

  auto stage = [&](int buf, int kt) {
#pragma unroll
    for (int i = 0; i < 4; ++i) {
      const int c   = i * 256 + t;
      const int row = c >> 3;
      const int kg  = (c & 7) ^ (row & 7);
      int ar = bm * 128 + row; ar = ar < M ? ar : M - 1;
      async16(&A[(size_t)ar * K + kt + kg * 8], &As[buf][c * 8]);
      const int br = bn * 128 + row;
      async16(&BT[(size_t)br * K + kt + kg * 8], &Bs[buf][c * 8]);
    }
  };

  stage(0, 0);
  __syncthreads();
  int cur = 0;

  for (int kt = 0; kt < K; kt += 64) {
    if (kt + 64 < K) stage(cur ^ 1, kt + 64);

#pragma unroll
    for (int kk = 0; kk < 2; ++kk) {
      short8 af[4], bfr[4];
#pragma unroll
      for (int m = 0; m < 4; ++m) {
        const int row = wm * 64 + m * 16 + l15;
        const int xb  = (kk * 64 + kq * 16) ^ ((row & 7) << 4);
        af[m] = *(const short8*)((const char*)&As[cur][0] + row * 128 + xb);
      }
#pragma unroll
      for (int n = 0; n < 4; ++n) {
        const int col = wn * 64 + n * 16 + l15;
        const int xb  = (kk * 64 + kq * 16) ^ ((col & 7) << 4);
        bfr[n] = *(const short8*)((const char*)&Bs[cur][0] + col * 128 + xb);
      }
#pragma unroll
      for (int m = 0; m < 4; ++m)
#pragma unroll
        for (int n = 0; n < 4; ++n)
          acc[m][n] = __builtin_amdgcn_mfma_f32_16x16x32_bf16(af[m], bfr[n], acc[m][n], 0, 0, 0);
    }

    __syncthreads();
    cur ^= 1;
  }

  const int crow0 = bm * 128 + wm * 64;
  const int ccol0 = bn * 128 + wn * 64;
#pragma unroll
  for (int n = 0; n < 4; ++n) {
    int col = ccol0 + n * 16 + l15;
    float bv = bias[col];
#pragma unroll
    for (int m = 0; m < 4; ++m) {
      int rbase = crow0 + m * 16 + kq * 4;
#pragma unroll
      for (int j = 0; j < 4; ++j) {
        int row = rbase + j;
        if (row < M) {
          float v = acc[m][n][j] + bv;
          if constexpr (OUT_MODE == 0) {
            ((float*)Cout)[(size_t)row * N + col] = v;
          } else {
            if constexpr (OUT_MODE == 2) v = fmaxf(v, 0.0f);
            ((u16*)Cout)[(size_t)row * N + col] = f2bf(v);
          }
        }
      }
    }
  }
}

// ---------------- fused FFN: out = relu(x@W1+b1)@W2 + b2 ----------------
// 512 threads (8 waves, 2x4). Block = 128 rows. DFF chunked by 64 (32 iters).
// LDS 144KB: xs[128][256] | w1s[64][256] | w2s[256][64] | ps[128][64], all bf16,
// all k-chunk XOR-swizzled (source-side on stage, same involution on ds_read).
__global__ __launch_bounds__(512, 2)
void ffn_fused(const u16* __restrict__ x_bf, const u16* __restrict__ W1T,
               const u16* __restrict__ W2T, const float* __restrict__ b1,
               const float* __restrict__ b2, float* __restrict__ out)
{
  extern __shared__ char smem[];
  u16* xs  = (u16*)(smem);            // [128][256] 64KB
  u16* w1s = (u16*)(smem + 65536);    // [64][256]  32KB
  u16* w2s = (u16*)(smem + 98304);    // [256][64]  32KB
  u16* ps  = (u16*)(smem + 131072);   // [128][64]  16KB

  const int t    = threadIdx.x;
  const int lane = t & 63;
  const int wid  = t >> 6;
  const int wm   = wid >> 2;          // 0..1 (row half)
  const int wn   = wid & 3;           // 0..3
  const int l15  = lane & 15;
  const int kq   = lane >> 4;
  const int bm   = blockIdx.x;

  // stage x tile once: 4096 16B chunks, rows of 512B (32 chunks)
#pragma unroll
  for (int i = 0; i < 8; ++i) {
    const int c   = i * 512 + t;
    const int row = c >> 5;
    const int kcs = (c & 31) ^ (row & 7);
    int ar = bm * 128 + row; ar = ar < MROWS ? ar : MROWS - 1;
    async16(&x_bf[(size_t)ar * 256 + kcs * 8], &xs[c * 8]);
  }

  f32x4 acc[4][4];
#pragma unroll
  for (int m = 0; m < 4; ++m)
#pragma unroll
    for (int n = 0; n < 4; ++n) acc[m][n] = (f32x4)0.0f;

  for (int it = 0; it < 32; ++it) {
    // stage W1 chunk [64][256] and W2 chunk [256][64]
#pragma unroll
    for (int i = 0; i < 4; ++i) {
      const int c  = i * 512 + t;
      const int r1 = c >> 5;
      const int k1 = ((c & 31) ^ (r1 & 7)) * 8;
      async16(&W1T[(size_t)(it * 64 + r1) * 256 + k1], &w1s[c * 8]);
      const int r2 = c >> 3;
      const int k2 = ((c & 7) ^ (r2 & 7)) * 8;
      async16(&W2T[(size_t)r2 * 2048 + it * 64 + k2], &w2s[c * 8]);
    }
    __syncthreads();   // drain stages (xs included on it==0)

    // P[128][64] = x @ W1c^T ; wave tile: rows wm*64+m*16, cols wn*16
    f32x4 p[4];
#pragma unroll
    for (int m = 0; m < 4; ++m) p[m] = (f32x4)0.0f;
#pragma unroll
    for (int ks = 0; ks < 8; ++ks) {
      const int wrow = wn * 16 + l15;
      const int wxb  = (ks * 64 + kq * 16) ^ ((wrow & 7) << 4);
      const short8 bf = *(const short8*)((const char*)w1s + wrow * 512 + wxb);
#pragma unroll
      for (int m = 0; m < 4; ++m) {
        const int arow = wm * 64 + m * 16 + l15;
        const int axb  = (ks * 64 + kq * 16) ^ ((arow & 7) << 4);
        const short8 af = *(const short8*)((const char*)xs + arow * 512 + axb);
        p[m] = __builtin_amdgcn_mfma_f32_16x16x32_bf16(af, bf, p[m], 0, 0, 0);
      }
    }

    // bias + relu + cvt bf16 -> ps (swizzled write)
    {
      const float bv = b1[it * 64 + wn * 16 + l15];
      const int pcol = wn * 16 + l15;
      const int chnk = pcol >> 3;          // 16B chunk within 128B row
      const int sub  = (pcol & 7) * 2;
#pragma unroll
      for (int m = 0; m < 4; ++m)
#pragma unroll
        for (int j = 0; j < 4; ++j) {
          const int prow = wm * 64 + m * 16 + kq * 4 + j;
          const float v = fmaxf(p[m][j] + bv, 0.0f);
          *(u16*)((char*)ps + prow * 128 + ((chnk ^ (prow & 7)) * 16) + sub) = f2bf(v);
        }
    }
    __syncthreads();   // ps visible; w1s free

    // acc += P @ W2c ; wave tile: rows wm*64, cols wn*64
#pragma unroll
    for (int kk = 0; kk < 2; ++kk) {
      short8 af[4], bfr[4];
#pragma unroll
      for (int m = 0; m < 4; ++m) {
        const int arow = wm * 64 + m * 16 + l15;
        const int axb  = ((kk * 4 + kq) ^ (arow & 7)) * 16;
        af[m] = *(const short8*)((const char*)ps + arow * 128 + axb);
      }
#pragma unroll
      for (int n = 0; n < 4; ++n) {
        const int brow = wn * 64 + n * 16 + l15;
        const int bxb  = ((kk * 4 + kq) ^ (brow & 7)) * 16;
        bfr[n] = *(const short8*)((const char*)w2s + brow * 128 + bxb);
      }
#pragma unroll
      for (int m = 0; m < 4; ++m)
#pragma unroll
        for (int n = 0; n < 4; ++n)
          acc[m][n] = __builtin_amdgcn_mfma_f32_16x16x32_bf16(af[m], bfr[n], acc[m][n], 0, 0, 0);
    }
    __syncthreads();   // ps & w2s free for next iter
  }

  // epilogue: f32, full-line stores (16 lanes x 4B = 64B per instr)
  const int crow0 = bm * 128 + wm * 64;
#pragma unroll
  for (int n = 0; n < 4; ++n) {
    const int col = wn * 64 + n * 16 + l15;
    const float bv = b2[col];
#pragma unroll
    for (int m = 0; m < 4; ++m) {
      const int rbase = crow0 + m * 16 + kq * 4;
#pragma unroll
      for (int j = 0; j < 4; ++j) {
        const int row = rbase + j;
        if (row < MROWS) out[(size_t)row * 256 + col] = acc[m][n][j] + bv;
      }
    }
  }
}

// ---------------- MS-deform sampler v2 ----------------
__global__ __launch_bounds__(256)
void sampler_kernel(const float* __restrict__ offattn,   // [M][384]
                    const float* __restrict__ refp,      // [M][4][2]
                    const u16*  __restrict__ value,      // [M][256] bf16
                    u16*        __restrict__ src2)       // [M][256] bf16
{
  __shared__ float2 sWI[2][8][65];

  const int t   = threadIdx.x;
  const int r2  = t >> 7;
  const int g   = t & 127;
  const int row = blockIdx.x * 2 + r2;
  const int b   = row / LQN;

  {
    const int h   = g >> 4;
    const int p16 = g & 15;
    const int l   = p16 >> 2;

    const float* oa = offattn + (size_t)row * 384;

    float logit = oa[256 + h * 16 + p16];
    float mx = logit;
#pragma unroll
    for (int o = 1; o < 16; o <<= 1) mx = fmaxf(mx, __shfl_xor(mx, o, 64));
    float e = __expf(logit - mx);
    float s = e;
#pragma unroll
    for (int o = 1; o < 16; o <<= 1) s += __shfl_xor(s, o, 64);
    const float aw = e / s;

    const int Wl = (l == 0) ? 100 : (l == 1) ? 50 : (l == 2) ? 25 : 13;
    const int Hl = Wl;
    const int st = (l == 0) ? 0 : (l == 1) ? 10000 : (l == 2) ? 12500 : 13125;

    const float ox = oa[(h * 16 + p16) * 2 + 0];
    const float oy = oa[(h * 16 + p16) * 2 + 1];
    const float rx = refp[(size_t)row * 8 + l * 2 + 0] * (float)Wl - 0.5f;
    const float ry = refp[(size_t)row * 8 + l * 2 + 1] * (float)Hl - 0.5f;
    const float gx = rx + ox;
    const float gy = ry + oy;
    const float x0f = floorf(gx), y0f = floorf(gy);
    const int   x0 = (int)x0f, y0 = (int)y0f;
    const float fx = gx - x0f, fy = gy - y0f;

#pragma unroll
    for (int c = 0; c < 4; ++c) {
      const int dx = c & 1, dy = c >> 1;
      const int xi = x0 + dx, yi = y0 + dy;
      const float wx = dx ? fx : 1.0f - fx;
      const float wy = dy ? fy : 1.0f - fy;
      const bool valid = (xi >= 0) && (xi < Wl) && (yi >= 0) && (yi < Hl);
      const int xc = min(max(xi, 0), Wl - 1);
      const int yc = min(max(yi, 0), Hl - 1);
      const int idx = st + yc * Wl + xc;
      const float w = wx * wy * aw * (valid ? 1.0f : 0.0f);
      sWI[r2][h][p16 * 4 + c] = make_float2(w, __builtin_bit_cast(float, idx));
    }
  }
  __syncthreads();

  {
    const int h  = g >> 4;
    const int c2 = g & 15;
    const char* vbase = (const char*)value + (size_t)b * LQN * 512 + h * 64 + c2 * 4;
    const float2* wi = sWI[r2][h];

    float acc0 = 0.f, acc1 = 0.f;
#pragma unroll 16
    for (int e = 0; e < 64; ++e) {
      const float2 p = wi[e];
      const float w  = p.x;
      const int  idx = __builtin_bit_cast(int, p.y);
      const unsigned u = *(const unsigned*)(vbase + (size_t)idx * 512);
      const float f0 = __builtin_bit_cast(float, u << 16);
      const float f1 = __builtin_bit_cast(float, u & 0xffff0000u);
      acc0 += f0 * w;
      acc1 += f1 * w;
    }
    const unsigned o = (unsigned)f2bf(acc0) | ((unsigned)f2bf(acc1) << 16);
    *(unsigned*)&src2[(size_t)row * 256 + h * 32 + c2 * 2] = o;
  }
}

// ---------------- LayerNorm(Xa + Xb): wave per row ----------------
template<int WRITE_BF>
__global__ __launch_bounds__(256)
void ln_kernel(const float* __restrict__ Xa, const float* __restrict__ Xb,
               const float* __restrict__ gam, const float* __restrict__ bet,
               float* __restrict__ Yf, u16* __restrict__ Ybf)
{
  const int wid = threadIdx.x >> 6, lane = threadIdx.x & 63;
  const int row = blockIdx.x * 4 + wid;
  const f32x4 va = ((const f32x4*)(Xa + (size_t)row * 256))[lane];
  const f32x4 vb = ((const f32x4*)(Xb + (size_t)row * 256))[lane];
  f32x4 v = va + vb;
  float s1 = v[0] + v[1] + v[2] + v[3];
  float s2 = v[0] * v[0] + v[1] * v[1] + v[2] * v[2] + v[3] * v[3];
#pragma unroll
  for (int off = 32; off; off >>= 1) {
    s1 += __shfl_xor(s1, off, 64);
    s2 += __shfl_xor(s2, off, 64);
  }
  const float mean = s1 * (1.0f / 256.0f);
  const float var  = s2 * (1.0f / 256.0f) - mean * mean;
  const float rstd = rsqrtf(var + 1e-5f);
  const f32x4 gv = ((const f32x4*)gam)[lane];
  const f32x4 bv = ((const f32x4*)bet)[lane];
  f32x4 y;
#pragma unroll
  for (int j = 0; j < 4; ++j) y[j] = (v[j] - mean) * rstd * gv[j] + bv[j];
  ((f32x4*)(Yf + (size_t)row * 256))[lane] = y;
  if constexpr (WRITE_BF) {
    u16x4 o;
#pragma unroll
    for (int j = 0; j < 4; ++j) o[j] = f2bf(y[j]);
    ((u16x4*)(Ybf + (size_t)row * 256))[lane] = o;
  }
}

// ---------------- prep ----------------
__global__ __launch_bounds__(256)
void prep_qsrc(const float* __restrict__ src, const float* __restrict__ pos,
               u16* __restrict__ src_bf, u16* __restrict__ q_bf)
{
  const size_t i = (size_t)blockIdx.x * 256 + threadIdx.x;
  const f32x4 s = ((const f32x4*)src)[i];
  const f32x4 p = ((const f32x4*)pos)[i];
  u16x4 sb, qb;
#pragma unroll
  for (int j = 0; j < 4; ++j) { sb[j] = f2bf(s[j]); qb[j] = f2bf(s[j] + p[j]); }
  ((u16x4*)src_bf)[i] = sb;
  ((u16x4*)q_bf)[i]   = qb;
}

__global__ __launch_bounds__(256)
void transpose_cast(const float* __restrict__ W, u16* __restrict__ WT, int K, int N)
{
  const int i = blockIdx.x * 256 + threadIdx.x;
  if (i >= K * N) return;
  const int k = i / N, n = i - k * N;
  WT[(size_t)n * K + k] = f2bf(W[i]);
}

__global__ __launch_bounds__(256)
void concat_bias(const float* __restrict__ b_off, const float* __restrict__ b_attn,
                 float* __restrict__ out)
{
  const int i = blockIdx.x * 256 + threadIdx.x;
  if (i < 256) out[i] = b_off[i];
  else if (i < 384) out[i] = b_attn[i - 256];
}

// ---------------- launch ----------------
extern "C" void kernel_launch(void* const* d_in, const int* in_sizes, int n_in,
                              void* d_out, int out_size, void* d_ws, size_t ws_size,
                              hipStream_t stream)
{
  const float* src     = (const float*)d_in[0];
  const float* pos     = (const float*)d_in[1];
  const float* refp    = (const float*)d_in[2];
  const float* w_value = (const float*)d_in[3];
  const float* b_value = (const float*)d_in[4];
  const float* w_off   = (const float*)d_in[5];
  const float* b_off   = (const float*)d_in[6];
  const float* w_attn  = (const float*)d_in[7];
  const float* b_attn  = (const float*)d_in[8];
  const float* w_out   = (const float*)d_in[9];
  const float* b_out   = (const float*)d_in[10];
  const float* ln1_g   = (const float*)d_in[11];
  const float* ln1_b   = (const float*)d_in[12];
  const float* w_ffn1  = (const float*)d_in[13];
  const float* b_ffn1  = (const float*)d_in[14];
  const float* w_ffn2  = (const float*)d_in[15];
  const float* b_ffn2  = (const float*)d_in[16];
  const float* ln2_g   = (const float*)d_in[17];
  const float* ln2_b   = (const float*)d_in[18];

  char* ws = (char*)d_ws;
  size_t off = 0;
  auto alloc = [&](size_t bytes) { void* p = ws + off; off += (bytes + 255) & ~(size_t)255; return p; };

  u16*   src_bf   = (u16*)  alloc((size_t)MROWS * 256 * 2);
  u16*   q_bf     = (u16*)  alloc((size_t)MROWS * 256 * 2);   // later: x_bf
  float* offattn  = (float*)alloc((size_t)MROWS * 384 * 4);   // later: src2p
  u16*   value_bf = (u16*)  alloc((size_t)MROWS * 256 * 2);   // later: ff (f32, spans src2_bf too)
  u16*   src2_bf  = (u16*)  alloc((size_t)MROWS * 256 * 2);
  float* x_f32    = (float*)alloc((size_t)MROWS * 256 * 4);
  u16*   WT_val   = (u16*)  alloc(256 * 256 * 2);
  u16*   WT_oa    = (u16*)  alloc(384 * 256 * 2);
  u16*   WT_out   = (u16*)  alloc(256 * 256 * 2);
  u16*   WT_f1    = (u16*)  alloc(2048 * 256 * 2);
  u16*   WT_f2    = (u16*)  alloc((size_t)256 * 2048 * 2);
  float* bias_oa  = (float*)alloc(384 * 4);

  float* src2p = offattn;            // alias (offattn dead after sampler)
  u16*   x_bf  = q_bf;               // alias (q_bf dead after offattn gemm)
  float* ff    = (float*)value_bf;   // alias (value/src2 dead after out-proj gemm)

  transpose_cast<<<256, 256, 0, stream>>>(w_value, WT_val, 256, 256);
  transpose_cast<<<256, 256, 0, stream>>>(w_off, WT_oa, 256, 256);
  transpose_cast<<<128, 256, 0, stream>>>(w_attn, WT_oa + 256 * 256, 256, 128);
  transpose_cast<<<256, 256, 0, stream>>>(w_out, WT_out, 256, 256);
  transpose_cast<<<2048, 256, 0, stream>>>(w_ffn1, WT_f1, 256, 2048);
  transpose_cast<<<2048, 256, 0, stream>>>(w_ffn2, WT_f2, 2048, 256);
  concat_bias<<<2, 256, 0, stream>>>(b_off, b_attn, bias_oa);

  prep_qsrc<<<6647, 256, 0, stream>>>(src, pos, src_bf, q_bf);

  gemm_bf16<1><<<dim3(208, 2), 256, 0, stream>>>(src_bf, WT_val, b_value, value_bf, MROWS, 256, 256);
  gemm_bf16<0><<<dim3(208, 3), 256, 0, stream>>>(q_bf, WT_oa, bias_oa, offattn, MROWS, 384, 256);

  sampler_kernel<<<MROWS / 2, 256, 0, stream>>>(offattn, refp, value_bf, src2_bf);

  gemm_bf16<0><<<dim3(208, 2), 256, 0, stream>>>(src2_bf, WT_out, b_out, src2p, MROWS, 256, 256);

  ln_kernel<1><<<6647, 256, 0, stream>>>(src, src2p, ln1_g, ln1_b, x_f32, x_bf);

  // fused FFN: ff = relu(x@W1+b1)@W2 + b2   (hbuf eliminated)
  static bool attr_set = false;
  if (!attr_set) {
    hipFuncSetAttribute((const void*)ffn_fused,
                        hipFuncAttributeMaxDynamicSharedMemorySize, 147456);
    attr_set = true;
  }
  ffn_fused<<<208, 512, 147456, stream>>>(x_bf, WT_f1, WT_f2, b_ffn1, b_ffn2, ff);

  ln_kernel<0><<<6647, 256, 0, stream>>>(x_f32, ff, ln2_g, ln2_b, (float*)d_out, nullptr);
}

// Round 5
// 252.310 us; speedup vs baseline: 2.5333x; 1.1411x over previous
//
#include <hip/hip_runtime.h>

// ---------------- static problem config ----------------
#define LQN   13294
#define NBAT  2
#define MROWS (NBAT * LQN)   // 26588
#define CCH   256
#define NHEAD 8
#define DHEAD 32
#define NLVL  4
#define NPT   4
#define DFF   2048

typedef short short8 __attribute__((ext_vector_type(8)));
typedef float f32x4 __attribute__((ext_vector_type(4)));
typedef unsigned short u16;
typedef u16 u16x4 __attribute__((ext_vector_type(4)));

__device__ __forceinline__ u16 f2bf(float f) {
  unsigned int u = __builtin_bit_cast(unsigned int, f);
  u += 0x7fffu + ((u >> 16) & 1u);   // RNE
  return (u16)(u >> 16);
}
__device__ __forceinline__ float bf2f(u16 s) {
  unsigned int u = ((unsigned int)s) << 16;
  return __builtin_bit_cast(float, u);
}
__device__ __forceinline__ void async16(const void* g, void* l) {
  __builtin_amdgcn_global_load_lds(
      (const __attribute__((address_space(1))) void*)g,
      (__attribute__((address_space(3))) void*)l, 16, 0, 0);
}

// ---------------- bf16 MFMA GEMM (r3): 2-phase dbuf, swizzled ----------------
// OUT_MODE: 0 = f32 out, 1 = bf16 out, 2 = bf16 out + relu
template<int OUT_MODE>
__global__ __launch_bounds__(256, 2)
void gemm_bf16(const u16* __restrict__ A, const u16* __restrict__ BT,
               const float* __restrict__ bias, void* __restrict__ Cout,
               int M, int N, int K)
{
  __shared__ u16 As[2][128 * 64];
  __shared__ u16 Bs[2][128 * 64];
  const int t    = threadIdx.x;
  const int lane = t & 63;
  const int wid  = t >> 6;
  const int wm   = wid >> 1, wn = wid & 1;
  const int bm   = blockIdx.x, bn = blockIdx.y;
  const int l15  = lane & 15;
  const int kq   = lane >> 4;

  f32x4 acc[4][4];
#pragma unroll
  for (int m = 0; m < 4; ++m)
#pragma unroll
    for (int n = 0; n < 4; ++n) acc[m][n] = (f32x4)0.0f;

  auto stage = [&](int buf, int kt) {
#pragma unroll
    for (int i = 0; i < 4; ++i) {
      const int c   = i * 256 + t;
      const int row = c >> 3;
      const int kg  = (c & 7) ^ (row & 7);
      int ar = bm * 128 + row; ar = ar < M ? ar : M - 1;
      async16(&A[(size_t)ar * K + kt + kg * 8], &As[buf][c * 8]);
      const int br = bn * 128 + row;
      async16(&BT[(size_t)br * K + kt + kg * 8], &Bs[buf][c * 8]);
    }
  };

  stage(0, 0);
  __syncthreads();
  int cur = 0;

  for (int kt = 0; kt < K; kt += 64) {
    if (kt + 64 < K) stage(cur ^ 1, kt + 64);

#pragma unroll
    for (int kk = 0; kk < 2; ++kk) {
      short8 af[4], bfr[4];
#pragma unroll
      for (int m = 0; m < 4; ++m) {
        const int row = wm * 64 + m * 16 + l15;
        const int xb  = (kk * 64 + kq * 16) ^ ((row & 7) << 4);
        af[m] = *(const short8*)((const char*)&As[cur][0] + row * 128 + xb);
      }
#pragma unroll
      for (int n = 0; n < 4; ++n) {
        const int col = wn * 64 + n * 16 + l15;
        const int xb  = (kk * 64 + kq * 16) ^ ((col & 7) << 4);
        bfr[n] = *(const short8*)((const char*)&Bs[cur][0] + col * 128 + xb);
      }
#pragma unroll
      for (int m = 0; m < 4; ++m)
#pragma unroll
        for (int n = 0; n < 4; ++n)
          acc[m][n] = __builtin_amdgcn_mfma_f32_16x16x32_bf16(af[m], bfr[n], acc[m][n], 0, 0, 0);
    }

    __syncthreads();
    cur ^= 1;
  }

  const int crow0 = bm * 128 + wm * 64;
  const int ccol0 = bn * 128 + wn * 64;
#pragma unroll
  for (int n = 0; n < 4; ++n) {
    int col = ccol0 + n * 16 + l15;
    float bv = bias[col];
#pragma unroll
    for (int m = 0; m < 4; ++m) {
      int rbase = crow0 + m * 16 + kq * 4;
#pragma unroll
      for (int j = 0; j < 4; ++j) {
        int row = rbase + j;
        if (row < M) {
          float v = acc[m][n][j] + bv;
          if constexpr (OUT_MODE == 0) {
            ((float*)Cout)[(size_t)row * N + col] = v;
          } else {
            if constexpr (OUT_MODE == 2) v = fmaxf(v, 0.0f);
            ((u16*)Cout)[(size_t)row * N + col] = f2bf(v);
          }
        }
      }
    }
  }
}

// ---------------- fused FFN v2: out = relu(x@W1+b1)@W2 + b2 ----------------
// 512 threads (8 waves). Block = 128 rows. DFF chunked by 64 (32 iters).
// x A-fragments cached in REGISTERS (loaded once from global, per-lane addrs).
// Weights double-buffered in LDS (prefetch it+1 before compute of it).
// ps interchange [128][80] bf16, stride 160B + chunk-XOR -> conflict-free.
// LDS: w1s 2x32KB | w2s 2x32KB | ps 20KB = 148KB (1 block/CU).
__global__ __launch_bounds__(512, 2)
void ffn_fused(const u16* __restrict__ x_bf, const u16* __restrict__ W1T,
               const u16* __restrict__ W2T, const float* __restrict__ b1,
               const float* __restrict__ b2, float* __restrict__ out)
{
  extern __shared__ char smem[];
  u16* w1s = (u16*)(smem);            // [2][64][256]
  u16* w2s = (u16*)(smem + 65536);    // [2][256][64]
  char* ps = (char*)(smem + 131072);  // [128][80] bf16 (160B row stride)

  const int t    = threadIdx.x;
  const int lane = t & 63;
  const int wid  = t >> 6;
  const int l15  = lane & 15;
  const int kq   = lane >> 4;
  const int bm   = blockIdx.x;
  // P-phase tiling: 8 waves = 4 row-groups x 2 col-groups, tile 32x32
  const int pwm  = wid >> 1, pwn = wid & 1;
  // PV-phase tiling: 8 waves = 2 row-groups x 4 col-groups, tile 64x64
  const int wm   = wid >> 2, wn = wid & 3;

  // ---- prologue: x fragments -> registers (once) ----
  short8 xr[2][8];
#pragma unroll
  for (int m = 0; m < 2; ++m) {
    int ar = bm * 128 + pwm * 32 + m * 16 + l15;
    ar = ar < MROWS ? ar : MROWS - 1;
    const char* xb = (const char*)x_bf + (size_t)ar * 512 + kq * 16;
#pragma unroll
    for (int ks = 0; ks < 8; ++ks)
      xr[m][ks] = *(const short8*)(xb + ks * 64);
  }

  auto stage = [&](int buf, int it) {
#pragma unroll
    for (int i = 0; i < 4; ++i) {
      const int c  = i * 512 + t;
      const int r1 = c >> 5;
      const int k1 = ((c & 31) ^ (r1 & 7)) * 8;
      async16(&W1T[(size_t)(it * 64 + r1) * 256 + k1], &w1s[buf * 16384 + c * 8]);
      const int r2 = c >> 3;
      const int k2 = ((c & 7) ^ (r2 & 7)) * 8;
      async16(&W2T[(size_t)r2 * 2048 + it * 64 + k2], &w2s[buf * 16384 + c * 8]);
    }
  };

  f32x4 acc[4][4];
#pragma unroll
  for (int m = 0; m < 4; ++m)
#pragma unroll
    for (int n = 0; n < 4; ++n) acc[m][n] = (f32x4)0.0f;

  stage(0, 0);
  __syncthreads();   // drain prologue stage (x reg loads waited on first use)

  for (int it = 0; it < 32; ++it) {
    const int cur = it & 1;
    if (it < 31) stage(cur ^ 1, it + 1);   // prefetch; drained at mid-iter barrier

    // ---- P = x @ W1c^T (wave tile 32x32), x from registers ----
    f32x4 p[2][2];
#pragma unroll
    for (int m = 0; m < 2; ++m)
#pragma unroll
      for (int n = 0; n < 2; ++n) p[m][n] = (f32x4)0.0f;

#pragma unroll
    for (int ks = 0; ks < 8; ++ks) {
      short8 bfr[2];
#pragma unroll
      for (int n = 0; n < 2; ++n) {
        const int wrow = pwn * 32 + n * 16 + l15;
        const int xb   = (ks * 64 + kq * 16) ^ ((wrow & 7) << 4);
        bfr[n] = *(const short8*)((const char*)&w1s[cur * 16384] + wrow * 512 + xb);
      }
#pragma unroll
      for (int m = 0; m < 2; ++m)
#pragma unroll
        for (int n = 0; n < 2; ++n)
          p[m][n] = __builtin_amdgcn_mfma_f32_16x16x32_bf16(xr[m][ks], bfr[n], p[m][n], 0, 0, 0);
    }

    // ---- bias + relu + bf16 -> ps (conflict-free scatter) ----
#pragma unroll
    for (int n = 0; n < 2; ++n) {
      const int col = pwn * 32 + n * 16 + l15;
      const float bv = b1[it * 64 + col];
      const int chnk = col >> 3;
      const int sub  = (col & 7) * 2;
#pragma unroll
      for (int m = 0; m < 2; ++m)
#pragma unroll
        for (int j = 0; j < 4; ++j) {
          const int prow = pwm * 32 + m * 16 + kq * 4 + j;
          const float v = fmaxf(p[m][n][j] + bv, 0.0f);
          *(u16*)(ps + prow * 160 + ((chnk ^ ((prow >> 2) & 3)) << 4) + sub) = f2bf(v);
        }
    }
    __syncthreads();   // ps visible; prefetch drained

    // ---- acc += P @ W2c (wave tile 64x64) ----
#pragma unroll
    for (int kk = 0; kk < 2; ++kk) {
      short8 paf[4], bfr[4];
#pragma unroll
      for (int m = 0; m < 4; ++m) {
        const int arow = wm * 64 + m * 16 + l15;
        const int c    = kk * 4 + kq;
        paf[m] = *(const short8*)(ps + arow * 160 + ((c ^ ((arow >> 2) & 3)) << 4));
      }
#pragma unroll
      for (int n = 0; n < 4; ++n) {
        const int brow = wn * 64 + n * 16 + l15;
        const int xb   = ((kk * 4 + kq) ^ (brow & 7)) * 16;
        bfr[n] = *(const short8*)((const char*)&w2s[cur * 16384] + brow * 128 + xb);
      }
#pragma unroll
      for (int m = 0; m < 4; ++m)
#pragma unroll
        for (int n = 0; n < 4; ++n)
          acc[m][n] = __builtin_amdgcn_mfma_f32_16x16x32_bf16(paf[m], bfr[n], acc[m][n], 0, 0, 0);
    }
    __syncthreads();   // all reads of ps / w2s[cur] done
  }

  // ---- epilogue: f32, full-line stores ----
  const int crow0 = bm * 128 + wm * 64;
#pragma unroll
  for (int n = 0; n < 4; ++n) {
    const int col = wn * 64 + n * 16 + l15;
    const float bv = b2[col];
#pragma unroll
    for (int m = 0; m < 4; ++m) {
      const int rbase = crow0 + m * 16 + kq * 4;
#pragma unroll
      for (int j = 0; j < 4; ++j) {
        const int row = rbase + j;
        if (row < MROWS) out[(size_t)row * 256 + col] = acc[m][n][j] + bv;
      }
    }
  }
}

// ---------------- MS-deform sampler v2 ----------------
__global__ __launch_bounds__(256)
void sampler_kernel(const float* __restrict__ offattn,   // [M][384]
                    const float* __restrict__ refp,      // [M][4][2]
                    const u16*  __restrict__ value,      // [M][256] bf16
                    u16*        __restrict__ src2)       // [M][256] bf16
{
  __shared__ float2 sWI[2][8][65];

  const int t   = threadIdx.x;
  const int r2  = t >> 7;
  const int g   = t & 127;
  const int row = blockIdx.x * 2 + r2;
  const int b   = row / LQN;

  {
    const int h   = g >> 4;
    const int p16 = g & 15;
    const int l   = p16 >> 2;

    const float* oa = offattn + (size_t)row * 384;

    float logit = oa[256 + h * 16 + p16];
    float mx = logit;
#pragma unroll
    for (int o = 1; o < 16; o <<= 1) mx = fmaxf(mx, __shfl_xor(mx, o, 64));
    float e = __expf(logit - mx);
    float s = e;
#pragma unroll
    for (int o = 1; o < 16; o <<= 1) s += __shfl_xor(s, o, 64);
    const float aw = e / s;

    const int Wl = (l == 0) ? 100 : (l == 1) ? 50 : (l == 2) ? 25 : 13;
    const int Hl = Wl;
    const int st = (l == 0) ? 0 : (l == 1) ? 10000 : (l == 2) ? 12500 : 13125;

    const float ox = oa[(h * 16 + p16) * 2 + 0];
    const float oy = oa[(h * 16 + p16) * 2 + 1];
    const float rx = refp[(size_t)row * 8 + l * 2 + 0] * (float)Wl - 0.5f;
    const float ry = refp[(size_t)row * 8 + l * 2 + 1] * (float)Hl - 0.5f;
    const float gx = rx + ox;
    const float gy = ry + oy;
    const float x0f = floorf(gx), y0f = floorf(gy);
    const int   x0 = (int)x0f, y0 = (int)y0f;
    const float fx = gx - x0f, fy = gy - y0f;

#pragma unroll
    for (int c = 0; c < 4; ++c) {
      const int dx = c & 1, dy = c >> 1;
      const int xi = x0 + dx, yi = y0 + dy;
      const float wx = dx ? fx : 1.0f - fx;
      const float wy = dy ? fy : 1.0f - fy;
      const bool valid = (xi >= 0) && (xi < Wl) && (yi >= 0) && (yi < Hl);
      const int xc = min(max(xi, 0), Wl - 1);
      const int yc = min(max(yi, 0), Hl - 1);
      const int idx = st + yc * Wl + xc;
      const float w = wx * wy * aw * (valid ? 1.0f : 0.0f);
      sWI[r2][h][p16 * 4 + c] = make_float2(w, __builtin_bit_cast(float, idx));
    }
  }
  __syncthreads();

  {
    const int h  = g >> 4;
    const int c2 = g & 15;
    const char* vbase = (const char*)value + (size_t)b * LQN * 512 + h * 64 + c2 * 4;
    const float2* wi = sWI[r2][h];

    float acc0 = 0.f, acc1 = 0.f;
#pragma unroll 16
    for (int e = 0; e < 64; ++e) {
      const float2 p = wi[e];
      const float w  = p.x;
      const int  idx = __builtin_bit_cast(int, p.y);
      const unsigned u = *(const unsigned*)(vbase + (size_t)idx * 512);
      const float f0 = __builtin_bit_cast(float, u << 16);
      const float f1 = __builtin_bit_cast(float, u & 0xffff0000u);
      acc0 += f0 * w;
      acc1 += f1 * w;
    }
    const unsigned o = (unsigned)f2bf(acc0) | ((unsigned)f2bf(acc1) << 16);
    *(unsigned*)&src2[(size_t)row * 256 + h * 32 + c2 * 2] = o;
  }
}

// ---------------- LayerNorm(Xa + Xb): wave per row ----------------
template<int WRITE_BF>
__global__ __launch_bounds__(256)
void ln_kernel(const float* __restrict__ Xa, const float* __restrict__ Xb,
               const float* __restrict__ gam, const float* __restrict__ bet,
               float* __restrict__ Yf, u16* __restrict__ Ybf)
{
  const int wid = threadIdx.x >> 6, lane = threadIdx.x & 63;
  const int row = blockIdx.x * 4 + wid;
  const f32x4 va = ((const f32x4*)(Xa + (size_t)row * 256))[lane];
  const f32x4 vb = ((const f32x4*)(Xb + (size_t)row * 256))[lane];
  f32x4 v = va + vb;
  float s1 = v[0] + v[1] + v[2] + v[3];
  float s2 = v[0] * v[0] + v[1] * v[1] + v[2] * v[2] + v[3] * v[3];
#pragma unroll
  for (int off = 32; off; off >>= 1) {
    s1 += __shfl_xor(s1, off, 64);
    s2 += __shfl_xor(s2, off, 64);
  }
  const float mean = s1 * (1.0f / 256.0f);
  const float var  = s2 * (1.0f / 256.0f) - mean * mean;
  const float rstd = rsqrtf(var + 1e-5f);
  const f32x4 gv = ((const f32x4*)gam)[lane];
  const f32x4 bv = ((const f32x4*)bet)[lane];
  f32x4 y;
#pragma unroll
  for (int j = 0; j < 4; ++j) y[j] = (v[j] - mean) * rstd * gv[j] + bv[j];
  ((f32x4*)(Yf + (size_t)row * 256))[lane] = y;
  if constexpr (WRITE_BF) {
    u16x4 o;
#pragma unroll
    for (int j = 0; j < 4; ++j) o[j] = f2bf(y[j]);
    ((u16x4*)(Ybf + (size_t)row * 256))[lane] = o;
  }
}

// ---------------- prep ----------------
__global__ __launch_bounds__(256)
void prep_qsrc(const float* __restrict__ src, const float* __restrict__ pos,
               u16* __restrict__ src_bf, u16* __restrict__ q_bf)
{
  const size_t i = (size_t)blockIdx.x * 256 + threadIdx.x;
  const f32x4 s = ((const f32x4*)src)[i];
  const f32x4 p = ((const f32x4*)pos)[i];
  u16x4 sb, qb;
#pragma unroll
  for (int j = 0; j < 4; ++j) { sb[j] = f2bf(s[j]); qb[j] = f2bf(s[j] + p[j]); }
  ((u16x4*)src_bf)[i] = sb;
  ((u16x4*)q_bf)[i]   = qb;
}

__global__ __launch_bounds__(256)
void transpose_cast(const float* __restrict__ W, u16* __restrict__ WT, int K, int N)
{
  const int i = blockIdx.x * 256 + threadIdx.x;
  if (i >= K * N) return;
  const int k = i / N, n = i - k * N;
  WT[(size_t)n * K + k] = f2bf(W[i]);
}

__global__ __launch_bounds__(256)
void concat_bias(const float* __restrict__ b_off, const float* __restrict__ b_attn,
                 float* __restrict__ out)
{
  const int i = blockIdx.x * 256 + threadIdx.x;
  if (i < 256) out[i] = b_off[i];
  else if (i < 384) out[i] = b_attn[i - 256];
}

// ---------------- launch ----------------
extern "C" void kernel_launch(void* const* d_in, const int* in_sizes, int n_in,
                              void* d_out, int out_size, void* d_ws, size_t ws_size,
                              hipStream_t stream)
{
  const float* src     = (const float*)d_in[0];
  const float* pos     = (const float*)d_in[1];
  const float* refp    = (const float*)d_in[2];
  const float* w_value = (const float*)d_in[3];
  const float* b_value = (const float*)d_in[4];
  const float* w_off   = (const float*)d_in[5];
  const float* b_off   = (const float*)d_in[6];
  const float* w_attn  = (const float*)d_in[7];
  const float* b_attn  = (const float*)d_in[8];
  const float* w_out   = (const float*)d_in[9];
  const float* b_out   = (const float*)d_in[10];
  const float* ln1_g   = (const float*)d_in[11];
  const float* ln1_b   = (const float*)d_in[12];
  const float* w_ffn1  = (const float*)d_in[13];
  const float* b_ffn1  = (const float*)d_in[14];
  const float* w_ffn2  = (const float*)d_in[15];
  const float* b_ffn2  = (const float*)d_in[16];
  const float* ln2_g   = (const float*)d_in[17];
  const float* ln2_b   = (const float*)d_in[18];

  char* ws = (char*)d_ws;
  size_t off = 0;
  auto alloc = [&](size_t bytes) { void* p = ws + off; off += (bytes + 255) & ~(size_t)255; return p; };

  u16*   src_bf   = (u16*)  alloc((size_t)MROWS * 256 * 2);
  u16*   q_bf     = (u16*)  alloc((size_t)MROWS * 256 * 2);   // later: x_bf
  float* offattn  = (float*)alloc((size_t)MROWS * 384 * 4);   // later: src2p
  u16*   value_bf = (u16*)  alloc((size_t)MROWS * 256 * 2);   // later: ff (f32, spans src2_bf too)
  u16*   src2_bf  = (u16*)  alloc((size_t)MROWS * 256 * 2);
  float* x_f32    = (float*)alloc((size_t)MROWS * 256 * 4);
  u16*   WT_val   = (u16*)  alloc(256 * 256 * 2);
  u16*   WT_oa    = (u16*)  alloc(384 * 256 * 2);
  u16*   WT_out   = (u16*)  alloc(256 * 256 * 2);
  u16*   WT_f1    = (u16*)  alloc(2048 * 256 * 2);
  u16*   WT_f2    = (u16*)  alloc((size_t)256 * 2048 * 2);
  float* bias_oa  = (float*)alloc(384 * 4);

  float* src2p = offattn;            // alias (offattn dead after sampler)
  u16*   x_bf  = q_bf;               // alias (q_bf dead after offattn gemm)
  float* ff    = (float*)value_bf;   // alias (value/src2 dead after out-proj gemm)

  transpose_cast<<<256, 256, 0, stream>>>(w_value, WT_val, 256, 256);
  transpose_cast<<<256, 256, 0, stream>>>(w_off, WT_oa, 256, 256);
  transpose_cast<<<128, 256, 0, stream>>>(w_attn, WT_oa + 256 * 256, 256, 128);
  transpose_cast<<<256, 256, 0, stream>>>(w_out, WT_out, 256, 256);
  transpose_cast<<<2048, 256, 0, stream>>>(w_ffn1, WT_f1, 256, 2048);
  transpose_cast<<<2048, 256, 0, stream>>>(w_ffn2, WT_f2, 2048, 256);
  concat_bias<<<2, 256, 0, stream>>>(b_off, b_attn, bias_oa);

  prep_qsrc<<<6647, 256, 0, stream>>>(src, pos, src_bf, q_bf);

  gemm_bf16<1><<<dim3(208, 2), 256, 0, stream>>>(src_bf, WT_val, b_value, value_bf, MROWS, 256, 256);
  gemm_bf16<0><<<dim3(208, 3), 256, 0, stream>>>(q_bf, WT_oa, bias_oa, offattn, MROWS, 384, 256);

  sampler_kernel<<<MROWS / 2, 256, 0, stream>>>(offattn, refp, value_bf, src2_bf);

  gemm_bf16<0><<<dim3(208, 2), 256, 0, stream>>>(src2_bf, WT_out, b_out, src2p, MROWS, 256, 256);

  ln_kernel<1><<<6647, 256, 0, stream>>>(src, src2p, ln1_g, ln1_b, x_f32, x_bf);

  // fused FFN: ff = relu(x@W1+b1)@W2 + b2
  static bool attr_set = false;
  if (!attr_set) {
    hipFuncSetAttribute((const void*)ffn_fused,
                        hipFuncAttributeMaxDynamicSharedMemorySize, 151552);
    attr_set = true;
  }
  ffn_fused<<<208, 512, 151552, stream>>>(x_bf, WT_f1, WT_f2, b_ffn1, b_ffn2, ff);

  ln_kernel<0><<<6647, 256, 0, stream>>>(x_f32, ff, ln2_g, ln2_b, (float*)d_out, nullptr);
}